// Round 5
// baseline (129.573 us; speedup 1.0000x reference)
//
#include <hip/hip_runtime.h>

#define T_ 4096   // B*S tokens
#define D_ 1024
#define E_ 8
#define MT 64
#define NT 128
#define KT 64     // k per LDS stage (16 K-steps, halved barrier count)

typedef __attribute__((ext_vector_type(8))) short short8;
typedef __attribute__((ext_vector_type(4))) float floatx4;

__device__ __forceinline__ unsigned short f2bf(float f) {
    union { float ff; unsigned int i; } v; v.ff = f;
    unsigned int i = v.i + 0x7fffu + ((v.i >> 16) & 1u);   // RNE
    return (unsigned short)(i >> 16);
}
__device__ __forceinline__ short8 pack8(float4 a, float4 b) {
    short8 r;
    r[0] = (short)f2bf(a.x); r[1] = (short)f2bf(a.y);
    r[2] = (short)f2bf(a.z); r[3] = (short)f2bf(a.w);
    r[4] = (short)f2bf(b.x); r[5] = (short)f2bf(b.y);
    r[6] = (short)f2bf(b.z); r[7] = (short)f2bf(b.w);
    return r;
}
__device__ __forceinline__ void glds16(const void* g, void* l) {
    __builtin_amdgcn_global_load_lds(
        (const __attribute__((address_space(1))) unsigned int*)g,
        (__attribute__((address_space(3))) unsigned int*)l, 16, 0, 0);
}

// ---- Router (no atomics) + x f32->bf16 + ew f32->bf16 slice ----
__global__ __launch_bounds__(256) void moe_router(
    const float* __restrict__ x,
    const float* __restrict__ rw,
    const float* __restrict__ rb,
    const float* __restrict__ ew,
    unsigned short* __restrict__ xbf,
    unsigned short* __restrict__ ewbf,
    float* __restrict__ wts,
    int*   __restrict__ top1)
{
    const int wave = threadIdx.x >> 6;
    const int lane = threadIdx.x & 63;
    const int tok  = blockIdx.x * 4 + wave;

    const float* xp = x + (size_t)tok * D_ + lane * 16;
    float4 xv[4];
    #pragma unroll
    for (int i = 0; i < 4; i++) xv[i] = *(const float4*)(xp + i * 4);

    unsigned short* xd = xbf + (size_t)tok * D_ + lane * 16;
    *(short8*)(xd)     = pack8(xv[0], xv[1]);
    *(short8*)(xd + 8) = pack8(xv[2], xv[3]);

    float xf[16];
    #pragma unroll
    for (int i = 0; i < 4; i++) {
        xf[i*4+0] = xv[i].x; xf[i*4+1] = xv[i].y;
        xf[i*4+2] = xv[i].z; xf[i*4+3] = xv[i].w;
    }

    float acc[E_];
    #pragma unroll
    for (int e = 0; e < E_; e++) {
        const float* wp = rw + e * D_ + lane * 16;
        float s = 0.f;
        #pragma unroll
        for (int i = 0; i < 4; i++) {
            float4 v = *(const float4*)(wp + i * 4);
            s += xf[i*4+0]*v.x + xf[i*4+1]*v.y + xf[i*4+2]*v.z + xf[i*4+3]*v.w;
        }
        acc[e] = s;
    }
    #pragma unroll
    for (int off = 32; off > 0; off >>= 1) {
        #pragma unroll
        for (int e = 0; e < E_; e++)
            acc[e] += __shfl_xor(acc[e], off, 64);
    }

    float lmax = -3.4e38f; int idx = 0;
    #pragma unroll
    for (int e = 0; e < E_; e++) {
        acc[e] += rb[e];
        if (acc[e] > lmax) { lmax = acc[e]; idx = e; }   // strict > = first max (numpy argmax)
    }
    float sum = 0.f;
    #pragma unroll
    for (int e = 0; e < E_; e++) sum += expf(acc[e] - lmax);

    if (lane == 0) {
        wts[tok]  = 1.0f / sum;
        top1[tok] = idx;
    }

    // ew convert: block slice of 8192 elems
    const size_t base = (size_t)blockIdx.x * 8192 + threadIdx.x * 8;
    #pragma unroll
    for (int j = 0; j < 4; j++) {
        size_t o = base + (size_t)j * 2048;
        float4 a = *(const float4*)(ew + o);
        float4 b = *(const float4*)(ew + o + 4);
        *(short8*)(ewbf + o) = pack8(a, b);
    }
}

// ---- Bucketize: 1 block, 8 waves, wave e compacts expert e via ballot (no atomics) ----
__global__ __launch_bounds__(512) void moe_bucketize(
    const int* __restrict__ top1,
    int* __restrict__ counts,
    int* __restrict__ bucket)
{
    __shared__ int lt[T_];
    for (int t = threadIdx.x; t < T_; t += 512) lt[t] = top1[t];
    __syncthreads();
    const int e    = threadIdx.x >> 6;     // wave -> expert
    const int lane = threadIdx.x & 63;
    const unsigned long long ltmask = (lane == 0) ? 0ull : (~0ull >> (64 - lane));
    int base = 0;
    for (int c = 0; c < T_ / 64; c++) {
        int t = c * 64 + lane;
        bool hit = (lt[t] == e);
        unsigned long long m = __ballot(hit);
        if (hit) bucket[e * T_ + base + __popcll(m & ltmask)] = t;
        base += __popcll(m);
    }
    if (lane == 0) counts[e] = base;
}

// ---- Grouped GEMM: 64x128 tile, KT=64, 2 blocks/CU, expert->XCD pinned ----
__global__ __launch_bounds__(256) void moe_gemm(
    const unsigned short* __restrict__ xbf,
    const unsigned short* __restrict__ ewbf,
    const float* __restrict__ eb,
    const float* __restrict__ wts,
    const int*  __restrict__ counts,
    const int*  __restrict__ bucket,
    float* __restrict__ out)
{
    const int bid = blockIdx.x;
    const int e   = bid & 7;            // consecutive bids -> XCD RR pins expert to XCD
    const int nb  = (bid >> 3) & 7;
    const int mt  = bid >> 6;           // 0..31
    const int cnt = counts[e];
    if (mt * MT >= cnt) return;
    const int n0 = nb * NT;

    __shared__ int   toks[MT];
    __shared__ float twt[MT];
    // Stage: rows 0..63 = A (tile rows), 64..191 = B (tile cols); row = 64 shorts (128 B),
    // 8 slots of 8 shorts; global k-chunk gc stored at slot gc^(row&7)
    __shared__ __align__(16) unsigned short Stage[(MT + NT) * KT];

    const int tid  = threadIdx.x;
    const int lane = tid & 63;
    const int w    = tid >> 6;
    const int wm   = w >> 1;            // 0/1: tile rows wm*32
    const int wn   = w & 1;             // 0/1: tile cols wn*64
    const int l16  = lane & 15;
    const int kq   = lane >> 4;         // 0..3

    // staging: 24 glds16 per stage, 6 per wave; instr j covers stage rows j*8..j*8+7
    int srow[6]; int sgc[6]; unsigned short* sdst[6];
    #pragma unroll
    for (int i = 0; i < 6; i++) {
        int j    = w * 6 + i;
        int row  = j * 8 + (lane >> 3);
        int slot = lane & 7;
        srow[i] = row;
        sgc[i]  = slot ^ (row & 7);
        sdst[i] = &Stage[j * 512];      // + lane*16B implicit in glds
    }
    const size_t ebase = (size_t)e << 20;

    for (int m0 = mt * MT; m0 < cnt; m0 += 32 * MT) {
        const int valid = min(MT, cnt - m0);
        __syncthreads();                // protect toks/twt (prev epilogue) before rewrite
        if (tid < MT) {
            int r = (tid < valid) ? tid : 0;
            int t = bucket[e * T_ + m0 + r];
            toks[tid] = t;
            twt[tid]  = wts[t];
        }
        __syncthreads();

        const unsigned short* src[6];
        #pragma unroll
        for (int i = 0; i < 6; i++) {
            int row = srow[i];
            src[i] = (row < MT)
                ? xbf + (size_t)toks[row] * D_ + sgc[i] * 8
                : ewbf + ebase + (size_t)(n0 + row - MT) * D_ + sgc[i] * 8;
        }

        floatx4 acc[2][4];
        #pragma unroll
        for (int mi = 0; mi < 2; mi++)
            #pragma unroll
            for (int ni = 0; ni < 4; ni++) acc[mi][ni] = (floatx4){0,0,0,0};

        for (int k0 = 0; k0 < D_; k0 += KT) {
            #pragma unroll
            for (int i = 0; i < 6; i++) glds16(src[i] + k0, sdst[i]);
            __syncthreads();

            short8 a[2][2], b[2][4];    // [k-half h][frag]
            #pragma unroll
            for (int mi = 0; mi < 2; mi++) {
                int ar = wm * 32 + mi * 16 + l16;
                #pragma unroll
                for (int h = 0; h < 2; h++)
                    a[h][mi] = *(const short8*)&Stage[ar * KT + ((h * 4 + kq) ^ (ar & 7)) * 8];
            }
            #pragma unroll
            for (int ni = 0; ni < 4; ni++) {
                int br = MT + wn * 64 + ni * 16 + l16;
                #pragma unroll
                for (int h = 0; h < 2; h++)
                    b[h][ni] = *(const short8*)&Stage[br * KT + ((h * 4 + kq) ^ (br & 7)) * 8];
            }
            #pragma unroll
            for (int h = 0; h < 2; h++)
                #pragma unroll
                for (int mi = 0; mi < 2; mi++)
                    #pragma unroll
                    for (int ni = 0; ni < 4; ni++)
                        acc[mi][ni] = __builtin_amdgcn_mfma_f32_16x16x32_bf16(
                            a[h][mi], b[h][ni], acc[mi][ni], 0, 0, 0);
            __syncthreads();
        }

        // epilogue: C/D layout col=lane&15, row=(lane>>4)*4+reg
        const int rq = kq * 4;
        #pragma unroll
        for (int ni = 0; ni < 4; ni++) {
            const int col  = n0 + wn * 64 + ni * 16 + l16;
            const float bias = eb[e * D_ + col];
            #pragma unroll
            for (int mi = 0; mi < 2; mi++) {
                #pragma unroll
                for (int r = 0; r < 4; r++) {
                    int row = wm * 32 + mi * 16 + rq + r;
                    if (row < valid)
                        out[(size_t)toks[row] * D_ + col] = (acc[mi][ni][r] + bias) * twt[row];
                }
            }
        }
    }
}

extern "C" void kernel_launch(void* const* d_in, const int* in_sizes, int n_in,
                              void* d_out, int out_size, void* d_ws, size_t ws_size,
                              hipStream_t stream) {
    (void)in_sizes; (void)n_in; (void)out_size; (void)ws_size;
    const float* x  = (const float*)d_in[0];
    const float* rw = (const float*)d_in[1];
    const float* rb = (const float*)d_in[2];
    const float* ew = (const float*)d_in[3];
    const float* eb = (const float*)d_in[4];
    float* out = (float*)d_out;

    // ws carve: xbf 8MB | ewbf 16MB | wts | top1 | counts | bucket
    unsigned short* xbf  = (unsigned short*)d_ws;
    unsigned short* ewbf = xbf + (size_t)T_ * D_;
    float* wts    = (float*)(ewbf + (size_t)E_ * D_ * D_);
    int*   top1   = (int*)(wts + T_);
    int*   counts = top1 + T_;
    int*   bucket = counts + E_;

    moe_router<<<dim3(T_ / 4), dim3(256), 0, stream>>>(x, rw, rb, ew, xbf, ewbf, wts, top1);
    moe_bucketize<<<dim3(1), dim3(512), 0, stream>>>(top1, counts, bucket);
    moe_gemm<<<dim3(2048), dim3(256), 0, stream>>>(xbf, ewbf, eb, wts, counts, bucket, out);
}